// Round 11
// baseline (148.095 us; speedup 1.0000x reference)
//
#include <hip/hip_runtime.h>

#define E_  1024
#define H_  16
#define B_  2
#define T_  2048
#define BT_ (B_*T_)   // 4096

typedef __bf16 bf16x8 __attribute__((ext_vector_type(8)));
typedef float  f32x4  __attribute__((ext_vector_type(4)));
typedef unsigned short u16x8 __attribute__((ext_vector_type(8)));

static __device__ __forceinline__ unsigned short f2bf(float x){
  unsigned int u = __float_as_uint(x);
  u += 0x7fffu + ((u >> 16) & 1u);
  return (unsigned short)(u >> 16);
}
static __device__ __forceinline__ float bf2f(unsigned short s){
  return __uint_as_float(((unsigned int)s) << 16);
}

static __device__ __forceinline__ void gld16(const unsigned short* g, unsigned short* l){
  __builtin_amdgcn_global_load_lds(
      (const __attribute__((address_space(1))) void*)g,
      (__attribute__((address_space(3))) void*)l, 16, 0, 0);
}

// blocks 0..2047: hidden->hb; 2048..4095: Wq,Wk,Wv->wqkv slab, Wo->wob
__global__ __launch_bounds__(256)
void cast_all(const float* __restrict__ hidden,
              const float* __restrict__ Wq, const float* __restrict__ Wk,
              const float* __restrict__ Wv, const float* __restrict__ Wo,
              unsigned short* __restrict__ hb,
              unsigned short* __restrict__ wqkv, unsigned short* __restrict__ wob){
  int bid = blockIdx.x;
  const float* src;
  unsigned short* dst;
  int off;
  if (bid < 2048) {
    src = hidden; dst = hb; off = bid * 2048 + threadIdx.x * 8;
  } else {
    int w = (bid - 2048) >> 9;
    off = ((bid - 2048) & 511) * 2048 + threadIdx.x * 8;
    src = (w==0) ? Wq : (w==1) ? Wk : (w==2) ? Wv : Wo;
    dst = (w==3) ? wob : (wqkv + (size_t)w * 1048576);
  }
  float4 v0 = *(const float4*)(src + off);
  float4 v1 = *(const float4*)(src + off + 4);
  u16x8 o;
  o[0]=f2bf(v0.x); o[1]=f2bf(v0.y); o[2]=f2bf(v0.z); o[3]=f2bf(v0.w);
  o[4]=f2bf(v1.x); o[5]=f2bf(v1.y); o[6]=f2bf(v1.z); o[7]=f2bf(v1.w);
  *(u16x8*)(dst + off) = o;
}

// Fused QKV GEMM: 128x128 tile, BK=32, 4 waves 2x2, global_load_lds w=16.
// N = 3072 split [Q|K|V]; q gets *0.125.
__global__ __launch_bounds__(256)
void gemm_qkv(const unsigned short* __restrict__ A,
              const unsigned short* __restrict__ Wqkv,
              const float* __restrict__ bq, const float* __restrict__ bk,
              const float* __restrict__ bv,
              unsigned short* __restrict__ Q, unsigned short* __restrict__ Ko,
              unsigned short* __restrict__ Vo)
{
  __shared__ unsigned short As[4096];   // 128 x 32, linear
  __shared__ unsigned short Bs[4096];
  const int tid = threadIdx.x;
  const int wv = tid >> 6, ln = tid & 63;
  const int wr = wv >> 1, wc = wv & 1;
  const int lr = ln & 15;
  const int lk8 = (ln >> 4) * 8;
  const int bm = blockIdx.x, bn = blockIdx.y;
  const size_t arow0 = (size_t)bm * 128;
  const size_t brow0 = (size_t)bn * 128;
  const int K = 1024;

  f32x4 acc[4][4];
  #pragma unroll
  for (int m = 0; m < 4; ++m)
    #pragma unroll
    for (int n = 0; n < 4; ++n) acc[m][n] = (f32x4){0.f,0.f,0.f,0.f};

  for (int k0 = 0; k0 < K; k0 += 32) {
    #pragma unroll
    for (int i = 0; i < 2; ++i) {
      int c = i*256 + wv*64 + ln;
      int row = c >> 2, off = (c & 3) * 8;
      gld16(A    + (arow0 + row) * K + k0 + off, As + (size_t)(i*256 + wv*64) * 8);
      gld16(Wqkv + (brow0 + row) * K + k0 + off, Bs + (size_t)(i*256 + wv*64) * 8);
    }
    __syncthreads();
    bf16x8 af[4], bf[4];
    #pragma unroll
    for (int m = 0; m < 4; ++m) af[m] = *(const bf16x8*)&As[(wr*64 + m*16 + lr)*32 + lk8];
    #pragma unroll
    for (int n = 0; n < 4; ++n) bf[n] = *(const bf16x8*)&Bs[(wc*64 + n*16 + lr)*32 + lk8];
    #pragma unroll
    for (int m = 0; m < 4; ++m)
      #pragma unroll
      for (int n = 0; n < 4; ++n)
        acc[m][n] = __builtin_amdgcn_mfma_f32_16x16x32_bf16(af[m], bf[n], acc[m][n], 0, 0, 0);
    __syncthreads();
  }

  const int which = bn >> 3;
  const float* bias = (which==0) ? bq : (which==1) ? bk : bv;
  unsigned short* Out = (which==0) ? Q : (which==1) ? Ko : Vo;
  const float scale = (which==0) ? 0.125f : 1.0f;
  #pragma unroll
  for (int n = 0; n < 4; ++n) {
    int col = (bn & 7)*128 + wc*64 + n*16 + lr;
    float bvv = bias[col];
    #pragma unroll
    for (int m = 0; m < 4; ++m) {
      int row0 = bm*128 + wr*64 + m*16 + (ln >> 4) * 4;
      #pragma unroll
      for (int r = 0; r < 4; ++r)
        Out[(size_t)(row0 + r) * 1024 + col] = f2bf((acc[m][n][r] + bvv) * scale);
    }
  }
}

// Partial M[d1][d2] = sum_{t in chunk} K[..d1]*V[..d2]; grid (32 bh, 16 chunks).
__global__ __launch_bounds__(256)
void ktv_partial(const unsigned short* __restrict__ Kmat,
                 const unsigned short* __restrict__ Vmat,
                 float* __restrict__ Mpart)
{
  __shared__ float Ks[32][64];
  __shared__ float Vs[32][64];
  const int tid   = threadIdx.x;
  const int bh    = blockIdx.x;   // 0..31
  const int chunk = blockIdx.y;   // 0..15
  const int b = bh >> 4, h = bh & 15;
  const int d2  = tid & 63;
  const int d1b = (tid >> 6) * 16;
  float acc[16];
  #pragma unroll
  for (int i = 0; i < 16; ++i) acc[i] = 0.f;
  const int row = tid >> 3, off = (tid & 7) * 8;
  const size_t base = ((size_t)b * T_) * E_ + (size_t)h * 64;

  for (int t0 = chunk * 128; t0 < chunk * 128 + 128; t0 += 32) {
    u16x8 kv = *(const u16x8*)(Kmat + base + (size_t)(t0 + row) * E_ + off);
    u16x8 vv = *(const u16x8*)(Vmat + base + (size_t)(t0 + row) * E_ + off);
    #pragma unroll
    for (int j = 0; j < 8; ++j) { Ks[row][off+j] = bf2f(kv[j]); Vs[row][off+j] = bf2f(vv[j]); }
    __syncthreads();
    for (int tt = 0; tt < 32; ++tt) {
      float vvv = Vs[tt][d2];
      #pragma unroll
      for (int i = 0; i < 16; ++i) acc[i] += Ks[tt][d1b + i] * vvv;
    }
    __syncthreads();
  }
  float* mp = Mpart + ((size_t)bh * 16 + chunk) * 4096;
  #pragma unroll
  for (int i = 0; i < 16; ++i) mp[(d1b + i) * 64 + d2] = acc[i];
}

// w2st_b[j, h*64+d1] = sum_d2 M_bh[d1,d2] * Wo[j, h*64+d2], where
// M_bh = (sum_chunks Mpart) * 0.125 is reduced HERE (fixed order, L2-hot).
// grid (32 bh, 16 j-tiles).
__global__ __launch_bounds__(256)
void w2s_reduce(const float* __restrict__ Mpart, const unsigned short* __restrict__ wob,
                unsigned short* __restrict__ w2st)
{
  __shared__ float MsT[64][65];            // MsT[d2][d1], padded
  __shared__ unsigned short Wos[64][64];   // Wos[j][d2]
  const int tid = threadIdx.x;
  const int bh  = blockIdx.x;
  const int j0  = blockIdx.y * 64;
  const int b = bh >> 4, h = bh & 15;

  // reduce the 16 Mpart chunks -> transposed LDS tile, *0.125
  #pragma unroll
  for (int j = 0; j < 16; ++j) {
    int i = j*256 + tid;                   // i = d1*64 + d2
    float s = 0.f;
    #pragma unroll
    for (int c = 0; c < 16; ++c) s += Mpart[((size_t)bh * 16 + c) * 4096 + i];
    MsT[i & 63][i >> 6] = s * 0.125f;
  }
  // stage the Wo tile: Wos[j][d2] = wob[(j0+j)*1024 + h*64 + d2]
  {
    int j = tid >> 2, c0 = (tid & 3) * 16;
    const unsigned short* src = wob + (size_t)(j0 + j) * 1024 + h*64 + c0;
    *(u16x8*)&Wos[j][c0]     = *(const u16x8*)(src);
    *(u16x8*)&Wos[j][c0 + 8] = *(const u16x8*)(src + 8);
  }
  __syncthreads();

  const int d1 = tid & 63;
  const int jbase = (tid >> 6) * 16;
  unsigned short* outp = w2st + ((size_t)b << 20) + (size_t)h * 64 + d1;
  #pragma unroll
  for (int jj = 0; jj < 16; ++jj) {
    int j = jbase + jj;
    float s = 0.f;
    #pragma unroll
    for (int d2 = 0; d2 < 64; ++d2) s += MsT[d2][d1] * bf2f(Wos[j][d2]);
    outp[(size_t)(j0 + j) * 1024] = f2bf(s);
  }
}

// Final GEMM: out[i,j] = sum_e qb[i,e]*w2st_b[j,e] + bo[j]; fp32 out.
// BM=128, BN=64, BK=32, grid (32, 16); batch z = bm>>4 selects w2st.
__global__ __launch_bounds__(256)
void gemm_final(const unsigned short* __restrict__ A,
                const unsigned short* __restrict__ w2st,
                const float* __restrict__ bias, float* __restrict__ C)
{
  __shared__ unsigned short As[4096];   // 128 x 32
  __shared__ unsigned short Bs[2048];   // 64 x 32
  const int tid = threadIdx.x;
  const int wv = tid >> 6, ln = tid & 63;
  const int wr = wv >> 1, wc = wv & 1;
  const int lr = ln & 15;
  const int lk8 = (ln >> 4) * 8;
  const int bm = blockIdx.x, bn = blockIdx.y;
  const unsigned short* Bw = w2st + ((size_t)(bm >> 4) << 20);
  const size_t arow0 = (size_t)bm * 128;
  const size_t brow0 = (size_t)bn * 64;
  const int K = 1024;

  f32x4 acc[4][2];
  #pragma unroll
  for (int m = 0; m < 4; ++m)
    #pragma unroll
    for (int n = 0; n < 2; ++n) acc[m][n] = (f32x4){0.f,0.f,0.f,0.f};

  for (int k0 = 0; k0 < K; k0 += 32) {
    #pragma unroll
    for (int i = 0; i < 2; ++i) {
      int c = i*256 + wv*64 + ln;
      int row = c >> 2, off = (c & 3) * 8;
      gld16(A + (arow0 + row) * K + k0 + off, As + (size_t)(i*256 + wv*64) * 8);
    }
    { int c = wv*64 + ln; int row = c >> 2, off = (c & 3) * 8;
      gld16(Bw + (size_t)(brow0 + row) * K + k0 + off, Bs + (size_t)(wv*64) * 8); }
    __syncthreads();
    bf16x8 af[4], bf[2];
    #pragma unroll
    for (int m = 0; m < 4; ++m) af[m] = *(const bf16x8*)&As[(wr*64 + m*16 + lr)*32 + lk8];
    #pragma unroll
    for (int n = 0; n < 2; ++n) bf[n] = *(const bf16x8*)&Bs[(wc*32 + n*16 + lr)*32 + lk8];
    #pragma unroll
    for (int m = 0; m < 4; ++m)
      #pragma unroll
      for (int n = 0; n < 2; ++n)
        acc[m][n] = __builtin_amdgcn_mfma_f32_16x16x32_bf16(af[m], bf[n], acc[m][n], 0, 0, 0);
    __syncthreads();
  }

  #pragma unroll
  for (int n = 0; n < 2; ++n) {
    int col = bn*64 + wc*32 + n*16 + lr;
    float bvv = bias[col];
    #pragma unroll
    for (int m = 0; m < 4; ++m) {
      int row0 = bm*128 + wr*64 + m*16 + (ln >> 4) * 4;
      #pragma unroll
      for (int r = 0; r < 4; ++r)
        C[(size_t)(row0 + r) * 1024 + col] = acc[m][n][r] + bvv;
    }
  }
}

extern "C" void kernel_launch(void* const* d_in, const int* in_sizes, int n_in,
                              void* d_out, int out_size, void* d_ws, size_t ws_size,
                              hipStream_t stream)
{
  const float* hidden = (const float*)d_in[0];
  const float* Wq = (const float*)d_in[1];
  const float* bq = (const float*)d_in[2];
  const float* Wk = (const float*)d_in[3];
  const float* bk = (const float*)d_in[4];
  const float* Wv = (const float*)d_in[5];
  const float* bv = (const float*)d_in[6];
  const float* Wo = (const float*)d_in[7];
  const float* bo = (const float*)d_in[8];
  float* out = (float*)d_out;

  const size_t SZ_ACT = (size_t)BT_ * E_;   // 4M elems
  const size_t SZ_W   = (size_t)E_ * E_;    // 1M elems

  char* p = (char*)d_ws;
  unsigned short* hb   = (unsigned short*)p; p += SZ_ACT * 2;
  unsigned short* wqkv = (unsigned short*)p; p += SZ_W * 3 * 2;
  unsigned short* wob  = (unsigned short*)p; p += SZ_W * 2;
  unsigned short* qb   = (unsigned short*)p; p += SZ_ACT * 2;
  unsigned short* kb   = (unsigned short*)p; p += SZ_ACT * 2;
  unsigned short* vb   = (unsigned short*)p; p += SZ_ACT * 2;
  unsigned short* w2st = (unsigned short*)p; p += SZ_W * 2 * 2;   // 2 batches
  float* Mpart = (float*)p; p += (size_t)32 * 16 * 4096 * 4;

  cast_all<<<4096, 256, 0, stream>>>(hidden, Wq, Wk, Wv, Wo, hb, wqkv, wob);

  gemm_qkv<<<dim3(32, 24), 256, 0, stream>>>(hb, wqkv, bq, bk, bv, qb, kb, vb);

  ktv_partial<<<dim3(32, 16), 256, 0, stream>>>(kb, vb, Mpart);
  w2s_reduce <<<dim3(32, 16), 256, 0, stream>>>(Mpart, wob, w2st);

  gemm_final<<<dim3(32, 16), 256, 0, stream>>>(qb, w2st, bo, out);
}

// Round 12
// 92.449 us; speedup vs baseline: 1.6019x; 1.6019x over previous
//
#include <hip/hip_runtime.h>

#define E_  1024
#define H_  16
#define B_  2
#define T_  2048
#define BT_ (B_*T_)   // 4096

typedef __bf16 bf16x8 __attribute__((ext_vector_type(8)));
typedef float  f32x4  __attribute__((ext_vector_type(4)));
typedef unsigned short u16x8 __attribute__((ext_vector_type(8)));

static __device__ __forceinline__ unsigned short f2bf(float x){
  unsigned int u = __float_as_uint(x);
  u += 0x7fffu + ((u >> 16) & 1u);
  return (unsigned short)(u >> 16);
}
static __device__ __forceinline__ float bf2f(unsigned short s){
  return __uint_as_float(((unsigned int)s) << 16);
}

static __device__ __forceinline__ void gld16(const unsigned short* g, unsigned short* l){
  __builtin_amdgcn_global_load_lds(
      (const __attribute__((address_space(1))) void*)g,
      (__attribute__((address_space(3))) void*)l, 16, 0, 0);
}

// blocks 0..2047: hidden->hb; 2048..4095: Wq,Wk,Wv->wqkv slab, Wo->wob
__global__ __launch_bounds__(256)
void cast_all(const float* __restrict__ hidden,
              const float* __restrict__ Wq, const float* __restrict__ Wk,
              const float* __restrict__ Wv, const float* __restrict__ Wo,
              unsigned short* __restrict__ hb,
              unsigned short* __restrict__ wqkv, unsigned short* __restrict__ wob){
  int bid = blockIdx.x;
  const float* src;
  unsigned short* dst;
  int off;
  if (bid < 2048) {
    src = hidden; dst = hb; off = bid * 2048 + threadIdx.x * 8;
  } else {
    int w = (bid - 2048) >> 9;
    off = ((bid - 2048) & 511) * 2048 + threadIdx.x * 8;
    src = (w==0) ? Wq : (w==1) ? Wk : (w==2) ? Wv : Wo;
    dst = (w==3) ? wob : (wqkv + (size_t)w * 1048576);
  }
  float4 v0 = *(const float4*)(src + off);
  float4 v1 = *(const float4*)(src + off + 4);
  u16x8 o;
  o[0]=f2bf(v0.x); o[1]=f2bf(v0.y); o[2]=f2bf(v0.z); o[3]=f2bf(v0.w);
  o[4]=f2bf(v1.x); o[5]=f2bf(v1.y); o[6]=f2bf(v1.z); o[7]=f2bf(v1.w);
  *(u16x8*)(dst + off) = o;
}

// Fused QKV GEMM: 128x128 tile, BK=32, 4 waves 2x2, global_load_lds w=16.
// N = 3072 split [Q|K|V]; q gets *0.125.
__global__ __launch_bounds__(256)
void gemm_qkv(const unsigned short* __restrict__ A,
              const unsigned short* __restrict__ Wqkv,
              const float* __restrict__ bq, const float* __restrict__ bk,
              const float* __restrict__ bv,
              unsigned short* __restrict__ Q, unsigned short* __restrict__ Ko,
              unsigned short* __restrict__ Vo)
{
  __shared__ unsigned short As[4096];   // 128 x 32, linear
  __shared__ unsigned short Bs[4096];
  const int tid = threadIdx.x;
  const int wv = tid >> 6, ln = tid & 63;
  const int wr = wv >> 1, wc = wv & 1;
  const int lr = ln & 15;
  const int lk8 = (ln >> 4) * 8;
  const int bm = blockIdx.x, bn = blockIdx.y;
  const size_t arow0 = (size_t)bm * 128;
  const size_t brow0 = (size_t)bn * 128;
  const int K = 1024;

  f32x4 acc[4][4];
  #pragma unroll
  for (int m = 0; m < 4; ++m)
    #pragma unroll
    for (int n = 0; n < 4; ++n) acc[m][n] = (f32x4){0.f,0.f,0.f,0.f};

  for (int k0 = 0; k0 < K; k0 += 32) {
    #pragma unroll
    for (int i = 0; i < 2; ++i) {
      int c = i*256 + wv*64 + ln;
      int row = c >> 2, off = (c & 3) * 8;
      gld16(A    + (arow0 + row) * K + k0 + off, As + (size_t)(i*256 + wv*64) * 8);
      gld16(Wqkv + (brow0 + row) * K + k0 + off, Bs + (size_t)(i*256 + wv*64) * 8);
    }
    __syncthreads();
    bf16x8 af[4], bf[4];
    #pragma unroll
    for (int m = 0; m < 4; ++m) af[m] = *(const bf16x8*)&As[(wr*64 + m*16 + lr)*32 + lk8];
    #pragma unroll
    for (int n = 0; n < 4; ++n) bf[n] = *(const bf16x8*)&Bs[(wc*64 + n*16 + lr)*32 + lk8];
    #pragma unroll
    for (int m = 0; m < 4; ++m)
      #pragma unroll
      for (int n = 0; n < 4; ++n)
        acc[m][n] = __builtin_amdgcn_mfma_f32_16x16x32_bf16(af[m], bf[n], acc[m][n], 0, 0, 0);
    __syncthreads();
  }

  const int which = bn >> 3;
  const float* bias = (which==0) ? bq : (which==1) ? bk : bv;
  unsigned short* Out = (which==0) ? Q : (which==1) ? Ko : Vo;
  const float scale = (which==0) ? 0.125f : 1.0f;
  #pragma unroll
  for (int n = 0; n < 4; ++n) {
    int col = (bn & 7)*128 + wc*64 + n*16 + lr;
    float bvv = bias[col];
    #pragma unroll
    for (int m = 0; m < 4; ++m) {
      int row0 = bm*128 + wr*64 + m*16 + (ln >> 4) * 4;
      #pragma unroll
      for (int r = 0; r < 4; ++r)
        Out[(size_t)(row0 + r) * 1024 + col] = f2bf((acc[m][n][r] + bvv) * scale);
    }
  }
}

// O-projection GEMM: BM=128, BN=64, BK=32, grid (32, 16) = 512 blocks.
__global__ __launch_bounds__(256)
void gemm_o(const unsigned short* __restrict__ A,
            const unsigned short* __restrict__ Bw,
            const float* __restrict__ bias, float* __restrict__ C)
{
  __shared__ unsigned short As[4096];   // 128 x 32
  __shared__ unsigned short Bs[2048];   // 64 x 32
  const int tid = threadIdx.x;
  const int wv = tid >> 6, ln = tid & 63;
  const int wr = wv >> 1, wc = wv & 1;
  const int lr = ln & 15;
  const int lk8 = (ln >> 4) * 8;
  const int bm = blockIdx.x, bn = blockIdx.y;
  const size_t arow0 = (size_t)bm * 128;
  const size_t brow0 = (size_t)bn * 64;
  const int K = 1024;

  f32x4 acc[4][2];
  #pragma unroll
  for (int m = 0; m < 4; ++m)
    #pragma unroll
    for (int n = 0; n < 2; ++n) acc[m][n] = (f32x4){0.f,0.f,0.f,0.f};

  for (int k0 = 0; k0 < K; k0 += 32) {
    #pragma unroll
    for (int i = 0; i < 2; ++i) {
      int c = i*256 + wv*64 + ln;
      int row = c >> 2, off = (c & 3) * 8;
      gld16(A + (arow0 + row) * K + k0 + off, As + (size_t)(i*256 + wv*64) * 8);
    }
    { int c = wv*64 + ln; int row = c >> 2, off = (c & 3) * 8;
      gld16(Bw + (brow0 + row) * K + k0 + off, Bs + (size_t)(wv*64) * 8); }
    __syncthreads();
    bf16x8 af[4], bf[2];
    #pragma unroll
    for (int m = 0; m < 4; ++m) af[m] = *(const bf16x8*)&As[(wr*64 + m*16 + lr)*32 + lk8];
    #pragma unroll
    for (int n = 0; n < 2; ++n) bf[n] = *(const bf16x8*)&Bs[(wc*32 + n*16 + lr)*32 + lk8];
    #pragma unroll
    for (int m = 0; m < 4; ++m)
      #pragma unroll
      for (int n = 0; n < 2; ++n)
        acc[m][n] = __builtin_amdgcn_mfma_f32_16x16x32_bf16(af[m], bf[n], acc[m][n], 0, 0, 0);
    __syncthreads();
  }

  #pragma unroll
  for (int n = 0; n < 2; ++n) {
    int col = bn*64 + wc*32 + n*16 + lr;
    float bvv = bias[col];
    #pragma unroll
    for (int m = 0; m < 4; ++m) {
      int row0 = bm*128 + wr*64 + m*16 + (ln >> 4) * 4;
      #pragma unroll
      for (int r = 0; r < 4; ++r)
        C[(size_t)(row0 + r) * 1024 + col] = acc[m][n][r] + bvv;
    }
  }
}

// Partial M[d1][d2] = sum_{t in chunk} K[..d1]*V[..d2]; grid (32 bh, 16 chunks).
__global__ __launch_bounds__(256)
void ktv_partial(const unsigned short* __restrict__ Kmat,
                 const unsigned short* __restrict__ Vmat,
                 float* __restrict__ Mpart)
{
  __shared__ float Ks[32][64];
  __shared__ float Vs[32][64];
  const int tid   = threadIdx.x;
  const int bh    = blockIdx.x;   // 0..31
  const int chunk = blockIdx.y;   // 0..15
  const int b = bh >> 4, h = bh & 15;
  const int d2  = tid & 63;
  const int d1b = (tid >> 6) * 16;
  float acc[16];
  #pragma unroll
  for (int i = 0; i < 16; ++i) acc[i] = 0.f;
  const int row = tid >> 3, off = (tid & 7) * 8;
  const size_t base = ((size_t)b * T_) * E_ + (size_t)h * 64;

  for (int t0 = chunk * 128; t0 < chunk * 128 + 128; t0 += 32) {
    u16x8 kv = *(const u16x8*)(Kmat + base + (size_t)(t0 + row) * E_ + off);
    u16x8 vv = *(const u16x8*)(Vmat + base + (size_t)(t0 + row) * E_ + off);
    #pragma unroll
    for (int j = 0; j < 8; ++j) { Ks[row][off+j] = bf2f(kv[j]); Vs[row][off+j] = bf2f(vv[j]); }
    __syncthreads();
    for (int tt = 0; tt < 32; ++tt) {
      float vvv = Vs[tt][d2];
      #pragma unroll
      for (int i = 0; i < 16; ++i) acc[i] += Ks[tt][d1b + i] * vvv;
    }
    __syncthreads();
  }
  float* mp = Mpart + ((size_t)bh * 16 + chunk) * 4096;
  #pragma unroll
  for (int i = 0; i < 16; ++i) mp[(d1b + i) * 64 + d2] = acc[i];
}

// MfinT[d2][d1] = bf16( (sum_chunks Mpart[d1][d2]) * 0.125 )
// Transposed + cast via padded LDS so both global passes stay coalesced.
__global__ __launch_bounds__(256)
void ktv_reduce(const float* __restrict__ Mpart, unsigned short* __restrict__ MfinT){
  __shared__ float Tl[64][65];
  const int bh = blockIdx.x;
  const int tid = threadIdx.x;
  #pragma unroll
  for (int j = 0; j < 16; ++j) {
    int i = j*256 + tid;              // i = d1*64 + d2
    float s = 0.f;
    #pragma unroll
    for (int c = 0; c < 16; ++c) s += Mpart[((size_t)bh * 16 + c) * 4096 + i];
    Tl[i & 63][i >> 6] = s * 0.125f;  // T[d2][d1]
  }
  __syncthreads();
  unsigned short* o = MfinT + (size_t)bh * 4096;
  #pragma unroll
  for (int j = 0; j < 16; ++j) {
    int i = j*256 + tid;              // i = d2*64 + d1
    o[i] = f2bf(Tl[i >> 6][i & 63]);
  }
}

// O[b,t,h*64+d2] = sum_d1 Q[b,t,h*64+d1] * M[d1][d2]  via MFMA, frags from
// global (L2-hot). Block = 32 t-rows x 1 head; wave wv owns cols wv*16..+15.
__global__ __launch_bounds__(256)
void qm_kernel(const unsigned short* __restrict__ Q,
               const unsigned short* __restrict__ MfinT,
               unsigned short* __restrict__ O)
{
  const int tid = threadIdx.x;
  const int wv = tid >> 6, ln = tid & 63;
  const int lr = ln & 15, lk8 = (ln >> 4) * 8;
  const int rb = blockIdx.x;       // 0..127
  const int h  = blockIdx.y;
  const int b  = rb >> 6;
  const int t0 = (rb & 63) * 32;
  const size_t base = ((size_t)b * T_) * E_ + (size_t)h * 64;
  const unsigned short* mt = MfinT + ((size_t)(b * 16 + h)) * 4096;

  bf16x8 af[2][2], bf[2];
  #pragma unroll
  for (int m = 0; m < 2; ++m)
    #pragma unroll
    for (int kk = 0; kk < 2; ++kk)
      af[m][kk] = *(const bf16x8*)(Q + base + (size_t)(t0 + m*16 + lr) * E_ + kk*32 + lk8);
  #pragma unroll
  for (int kk = 0; kk < 2; ++kk)
    bf[kk] = *(const bf16x8*)(mt + (wv*16 + lr) * 64 + kk*32 + lk8);

  f32x4 acc[2] = {(f32x4){0.f,0.f,0.f,0.f}, (f32x4){0.f,0.f,0.f,0.f}};
  #pragma unroll
  for (int m = 0; m < 2; ++m)
    #pragma unroll
    for (int kk = 0; kk < 2; ++kk)
      acc[m] = __builtin_amdgcn_mfma_f32_16x16x32_bf16(af[m][kk], bf[kk], acc[m], 0, 0, 0);

  const int col = wv*16 + lr;
  #pragma unroll
  for (int m = 0; m < 2; ++m) {
    int row0 = t0 + m*16 + (ln >> 4) * 4;
    #pragma unroll
    for (int r = 0; r < 4; ++r)
      O[base + (size_t)(row0 + r) * E_ + col] = f2bf(acc[m][r]);
  }
}

extern "C" void kernel_launch(void* const* d_in, const int* in_sizes, int n_in,
                              void* d_out, int out_size, void* d_ws, size_t ws_size,
                              hipStream_t stream)
{
  const float* hidden = (const float*)d_in[0];
  const float* Wq = (const float*)d_in[1];
  const float* bq = (const float*)d_in[2];
  const float* Wk = (const float*)d_in[3];
  const float* bk = (const float*)d_in[4];
  const float* Wv = (const float*)d_in[5];
  const float* bv = (const float*)d_in[6];
  const float* Wo = (const float*)d_in[7];
  const float* bo = (const float*)d_in[8];
  float* out = (float*)d_out;

  const size_t SZ_ACT = (size_t)BT_ * E_;   // 4M elems
  const size_t SZ_W   = (size_t)E_ * E_;    // 1M elems

  char* p = (char*)d_ws;
  unsigned short* hb    = (unsigned short*)p; p += SZ_ACT * 2;
  unsigned short* wqkv  = (unsigned short*)p; p += SZ_W * 3 * 2;
  unsigned short* wob   = (unsigned short*)p; p += SZ_W * 2;
  unsigned short* qb    = (unsigned short*)p; p += SZ_ACT * 2;
  unsigned short* kb    = (unsigned short*)p; p += SZ_ACT * 2;
  unsigned short* vb    = (unsigned short*)p; p += SZ_ACT * 2;
  unsigned short* ob    = (unsigned short*)p; p += SZ_ACT * 2;
  float* Mpart = (float*)p; p += (size_t)32 * 16 * 4096 * 4;
  unsigned short* MfinT = (unsigned short*)p; p += (size_t)32 * 4096 * 2;

  cast_all<<<4096, 256, 0, stream>>>(hidden, Wq, Wk, Wv, Wo, hb, wqkv, wob);

  gemm_qkv<<<dim3(32, 24), 256, 0, stream>>>(hb, wqkv, bq, bk, bv, qb, kb, vb);

  ktv_partial<<<dim3(32, 16), 256, 0, stream>>>(kb, vb, Mpart);
  ktv_reduce <<<32, 256, 0, stream>>>(Mpart, MfinT);
  qm_kernel  <<<dim3(128, 16), 256, 0, stream>>>(qb, MfinT, ob);

  gemm_o<<<dim3(32, 16), 256, 0, stream>>>(ob, wob, bo, out);
}